// Round 3
// baseline (1598.947 us; speedup 1.0000x reference)
//
#include <hip/hip_runtime.h>
#include <hip/hip_fp16.h>

#define B_  32
#define T_  2048
#define I_  256
#define H_  128

typedef _Float16 f16;
typedef _Float16 f16x4 __attribute__((ext_vector_type(4)));
typedef _Float16 f16x8 __attribute__((ext_vector_type(8)));
typedef float    f32x4 __attribute__((ext_vector_type(4)));

// sigmoid(x) = 1/(1+2^(-x*log2e));  tanh(x) = 2/(1+2^(-2x*log2e)) - 1
static __device__ __forceinline__ float fast_sig(float x) {
  float e = __builtin_amdgcn_exp2f(-1.44269504089f * x);
  return __builtin_amdgcn_rcpf(1.0f + e);
}
static __device__ __forceinline__ float fast_tanh(float x) {
  float e = __builtin_amdgcn_exp2f(-2.88539008178f * x);
  return 2.0f * __builtin_amdgcn_rcpf(1.0f + e) - 1.0f;
}

// LDS-only barrier: do NOT drain vmcnt -- global prefetch loads and out[]
// stores float across steps.  sched_barrier(0) fences per rule #18.
#define BARRIER_LDS()                                   \
  __builtin_amdgcn_sched_barrier(0);                    \
  asm volatile("s_waitcnt lgkmcnt(0)" ::: "memory");    \
  __builtin_amdgcn_s_barrier();                         \
  __builtin_amdgcn_sched_barrier(0)

// ---------------------------------------------------------------------------
// Kernel 1: xg[m][n] = sum_k x[m][k] * W'[n][k] + b_ih[n] + b_hh[n]
//   (unchanged from round 2 -- ~80 us, not the bottleneck)
// ---------------------------------------------------------------------------
__global__ __launch_bounds__(256) void xg_gemm(
    const float* __restrict__ x,
    const float* __restrict__ Wf, const float* __restrict__ Wb,
    const float* __restrict__ bf_ih, const float* __restrict__ bf_hh,
    const float* __restrict__ bb_ih, const float* __restrict__ bb_hh,
    f16* __restrict__ xg)
{
  __shared__ f16 xs[128][136];   // +8 f16 pad
  __shared__ f16 wt[128][136];

  const int tid = threadIdx.x;
  const int m0  = blockIdx.y * 128;
  const int n0  = blockIdx.x * 128;

  const float* Wsrc; const float* bih; const float* bhh; int nb;
  if (n0 < 512) { Wsrc = Wf; bih = bf_ih; bhh = bf_hh; nb = n0; }
  else          { Wsrc = Wb; bih = bb_ih; bhh = bb_hh; nb = n0 - 512; }

  const int w  = tid >> 6;           // wave 0..3 -> rows [32w, 32w+32)
  const int l  = tid & 63;
  const int lr = l & 15;
  const int lk = (l >> 4) * 8;

  f32x4 acc[2][8] = {};

  #pragma unroll
  for (int kh = 0; kh < 2; ++kh) {
    #pragma unroll
    for (int it = 0; it < 16; ++it) {
      int idx = it * 256 + tid;
      int row = idx >> 5, c4 = idx & 31;
      float4 v = *(const float4*)&x[(size_t)(m0 + row) * I_ + kh * 128 + c4 * 4];
      f16x4 h4 = { (f16)v.x, (f16)v.y, (f16)v.z, (f16)v.w };
      *(f16x4*)&xs[row][c4 * 4] = h4;
    }
    #pragma unroll
    for (int it = 0; it < 16; ++it) {
      int idx = it * 256 + tid;
      int row = idx >> 5, c4 = idx & 31;
      float4 v = *(const float4*)&Wsrc[(size_t)(nb + row) * I_ + kh * 128 + c4 * 4];
      f16x4 h4 = { (f16)v.x, (f16)v.y, (f16)v.z, (f16)v.w };
      *(f16x4*)&wt[row][c4 * 4] = h4;
    }
    __syncthreads();

    #pragma unroll
    for (int ks = 0; ks < 4; ++ks) {
      int kk = ks * 32 + lk;
      f16x8 a0 = *(const f16x8*)&xs[w * 32 + lr][kk];
      f16x8 a1 = *(const f16x8*)&xs[w * 32 + 16 + lr][kk];
      #pragma unroll
      for (int nt = 0; nt < 8; ++nt) {
        f16x8 bf = *(const f16x8*)&wt[nt * 16 + lr][kk];
        acc[0][nt] = __builtin_amdgcn_mfma_f32_16x16x32_f16(a0, bf, acc[0][nt], 0, 0, 0);
        acc[1][nt] = __builtin_amdgcn_mfma_f32_16x16x32_f16(a1, bf, acc[1][nt], 0, 0, 0);
      }
    }
    __syncthreads();
  }

  #pragma unroll
  for (int mt = 0; mt < 2; ++mt) {
    #pragma unroll
    for (int nt = 0; nt < 8; ++nt) {
      int nloc = nt * 16 + lr;
      float bias = bih[nb + nloc] + bhh[nb + nloc];
      #pragma unroll
      for (int r = 0; r < 4; ++r) {
        int m = m0 + w * 32 + mt * 16 + (l >> 4) * 4 + r;
        xg[(size_t)m * 1024 + n0 + nloc] = (f16)(acc[mt][nt][r] + bias);
      }
    }
  }
}

// ---------------------------------------------------------------------------
// Kernel 2: recurrence via MFMA.  One 512-thread WG (8 waves) per (dir,b).
//   gates(1x512) = h(1x128) @ W_hh^T via mfma_f32_16x16x32_f16 with M=1
//   (A = h replicated across all 16 rows; D rows identical, row 0 used).
//   Wave w owns N-tiles {w, 8+w, 16+w, 24+w} = gates i,f,g,o of units
//   w*16+c  ->  i,f,g,o land lane-local in lanes 0..15 (acc[q][0]).
//   W_hh B-fragments live in 64 VGPRs; h double-buffered in 512 B LDS;
//   xg folded in as the C initializer, prefetched 2 steps ahead.
//   One LDS-only barrier per step.
// ---------------------------------------------------------------------------
__global__ __launch_bounds__(512, 1) void birnn_rec(
    const f16* __restrict__ xg,
    const float* __restrict__ Wfhh, const float* __restrict__ Wbhh,
    const int* __restrict__ lengths,
    float* __restrict__ out)
{
  const int tid  = threadIdx.x;
  const int wave = tid >> 6;
  const int l    = tid & 63;
  const int c    = l & 15;        // column within 16-wide tile
  const int kgrp = l >> 4;        // k-chunk group (8 f16 each)
  const int dir  = blockIdx.x >> 5;
  const int b    = blockIdx.x & 31;
  const float* Whh = dir ? Wbhh : Wfhh;
  const int L    = lengths[b];

  // B-fragments: bfrag[q][ks] = W_hh[n = q*128 + wave*16 + c][ks*32 + kgrp*8 ..+8]
  f16x8 bfrag[4][4];
  #pragma unroll
  for (int q = 0; q < 4; ++q) {
    int n = q * 128 + wave * 16 + c;
    #pragma unroll
    for (int ks = 0; ks < 4; ++ks) {
      int k0 = ks * 32 + kgrp * 8;
      float4 va = *(const float4*)&Whh[(size_t)n * H_ + k0];
      float4 vb = *(const float4*)&Whh[(size_t)n * H_ + k0 + 4];
      bfrag[q][ks] = (f16x8){ (f16)va.x, (f16)va.y, (f16)va.z, (f16)va.w,
                              (f16)vb.x, (f16)vb.y, (f16)vb.z, (f16)vb.w };
    }
  }

  __shared__ __align__(16) f16 hbuf[2][128];
  if (tid < 128) hbuf[0][tid] = (f16)0.0f;
  float cstate = 0.0f;
  __syncthreads();

  auto rowof = [&](int t) -> size_t {
    int it = t;
    if (dir) it = (t < L) ? (L - 1 - t) : t;
    return ((size_t)(b * T_ + it)) * 1024 + (size_t)dir * 512;
  };
  const int goff = wave * 16 + c;

  // depth-2 xg prefetch (arrays fully unrolled -> static indices -> registers)
  f16 pa[4], pb[4];
  {
    size_t r0 = rowof(0), r1 = rowof(1);
    #pragma unroll
    for (int q = 0; q < 4; ++q) {
      pa[q] = xg[r0 + q * 128 + goff];
      pb[q] = xg[r1 + q * 128 + goff];
    }
  }

  const bool row0 = (l < 16);

#define STEP(t, P, HR, HW)                                                    \
  {                                                                           \
    f32x4 a0 = {}, a1 = {}, a2 = {}, a3 = {};                                 \
    a0[0] = row0 ? (float)P[0] : 0.0f;                                        \
    a1[0] = row0 ? (float)P[1] : 0.0f;                                        \
    a2[0] = row0 ? (float)P[2] : 0.0f;                                        \
    a3[0] = row0 ? (float)P[3] : 0.0f;                                        \
    if ((t) + 2 < T_) {                                                       \
      size_t r2 = rowof((t) + 2);                                             \
      P[0] = xg[r2 + 0 * 128 + goff];                                         \
      P[1] = xg[r2 + 1 * 128 + goff];                                         \
      P[2] = xg[r2 + 2 * 128 + goff];                                         \
      P[3] = xg[r2 + 3 * 128 + goff];                                         \
    }                                                                         \
    f16x8 af0 = *(const f16x8*)&(HR)[kgrp * 8];                               \
    f16x8 af1 = *(const f16x8*)&(HR)[32 + kgrp * 8];                          \
    f16x8 af2 = *(const f16x8*)&(HR)[64 + kgrp * 8];                          \
    f16x8 af3 = *(const f16x8*)&(HR)[96 + kgrp * 8];                          \
    a0 = __builtin_amdgcn_mfma_f32_16x16x32_f16(af0, bfrag[0][0], a0, 0, 0, 0); \
    a1 = __builtin_amdgcn_mfma_f32_16x16x32_f16(af0, bfrag[1][0], a1, 0, 0, 0); \
    a2 = __builtin_amdgcn_mfma_f32_16x16x32_f16(af0, bfrag[2][0], a2, 0, 0, 0); \
    a3 = __builtin_amdgcn_mfma_f32_16x16x32_f16(af0, bfrag[3][0], a3, 0, 0, 0); \
    a0 = __builtin_amdgcn_mfma_f32_16x16x32_f16(af1, bfrag[0][1], a0, 0, 0, 0); \
    a1 = __builtin_amdgcn_mfma_f32_16x16x32_f16(af1, bfrag[1][1], a1, 0, 0, 0); \
    a2 = __builtin_amdgcn_mfma_f32_16x16x32_f16(af1, bfrag[2][1], a2, 0, 0, 0); \
    a3 = __builtin_amdgcn_mfma_f32_16x16x32_f16(af1, bfrag[3][1], a3, 0, 0, 0); \
    a0 = __builtin_amdgcn_mfma_f32_16x16x32_f16(af2, bfrag[0][2], a0, 0, 0, 0); \
    a1 = __builtin_amdgcn_mfma_f32_16x16x32_f16(af2, bfrag[1][2], a1, 0, 0, 0); \
    a2 = __builtin_amdgcn_mfma_f32_16x16x32_f16(af2, bfrag[2][2], a2, 0, 0, 0); \
    a3 = __builtin_amdgcn_mfma_f32_16x16x32_f16(af2, bfrag[3][2], a3, 0, 0, 0); \
    a0 = __builtin_amdgcn_mfma_f32_16x16x32_f16(af3, bfrag[0][3], a0, 0, 0, 0); \
    a1 = __builtin_amdgcn_mfma_f32_16x16x32_f16(af3, bfrag[1][3], a1, 0, 0, 0); \
    a2 = __builtin_amdgcn_mfma_f32_16x16x32_f16(af3, bfrag[2][3], a2, 0, 0, 0); \
    a3 = __builtin_amdgcn_mfma_f32_16x16x32_f16(af3, bfrag[3][3], a3, 0, 0, 0); \
    if (row0) {                                                               \
      float is = fast_sig(a0[0]);                                             \
      float fs = fast_sig(a1[0]);                                             \
      float gt = fast_tanh(a2[0]);                                            \
      float os = fast_sig(a3[0]);                                             \
      cstate = fs * cstate + is * gt;                                         \
      float hval = os * fast_tanh(cstate);                                    \
      (HW)[goff] = (f16)hval;                                                 \
      out[((size_t)(b * T_ + (t))) * 256 + dir * 128 + goff] = hval;          \
    }                                                                         \
    BARRIER_LDS();                                                            \
  }

  for (int tt = 0; tt < T_; tt += 2) {
    STEP(tt,     pa, hbuf[0], hbuf[1]);
    STEP(tt + 1, pb, hbuf[1], hbuf[0]);
  }
#undef STEP
}

// ---------------------------------------------------------------------------
extern "C" void kernel_launch(void* const* d_in, const int* in_sizes, int n_in,
                              void* d_out, int out_size, void* d_ws, size_t ws_size,
                              hipStream_t stream) {
  const float* x      = (const float*)d_in[0];
  const int*   lengths= (const int*)  d_in[1];
  const float* Wf_ih  = (const float*)d_in[2];
  const float* Wf_hh  = (const float*)d_in[3];
  const float* bf_ih  = (const float*)d_in[4];
  const float* bf_hh  = (const float*)d_in[5];
  const float* Wb_ih  = (const float*)d_in[6];
  const float* Wb_hh  = (const float*)d_in[7];
  const float* bb_ih  = (const float*)d_in[8];
  const float* bb_hh  = (const float*)d_in[9];
  float* out = (float*)d_out;
  f16*   xg  = (f16*)d_ws;   // needs B*T*1024*2 = 134,217,728 bytes

  (void)in_sizes; (void)n_in; (void)out_size; (void)ws_size;

  xg_gemm<<<dim3(8, 512), 256, 0, stream>>>(x, Wf_ih, Wb_ih,
                                            bf_ih, bf_hh, bb_ih, bb_hh, xg);
  birnn_rec<<<dim3(64), 512, 0, stream>>>(xg, Wf_hh, Wb_hh, lengths, out);
}